// Round 6
// baseline (122.684 us; speedup 1.0000x reference)
//
#include <hip/hip_runtime.h>

#define HH 480
#define WW 640
#define NPIX (HH * WW)
#define BB 16
#define PPT 4                      // pixels per thread
#define BLK 256
#define GX (NPIX / (BLK * PPT))    // 300 blocks along pixel dim
#define NPART (GX * BB * 2)        // 9600 block partials

// ws layout: [bf16 depth0 images][bf16 depth1 images][float partials]
#define BF0_OFF 0
#define BF1_OFF ((size_t)BB * NPIX * 2)
#define PART_OFF ((size_t)2 * BB * NPIX * 2)

struct __attribute__((packed, aligned(2))) u32u { unsigned int v; };

__device__ __forceinline__ unsigned short f2bf_rne(float f) {
    unsigned int u = __float_as_uint(f);
    unsigned int r = (u + 0x7fffu + ((u >> 16) & 1u)) >> 16;
    return (unsigned short)r;
}

// Convert depth0+depth1 (fp32) to bf16 copies in ws. Fully coalesced.
// 8 pixels per thread: 2x float4 load -> uint4 store (8 bf16).
__global__ __launch_bounds__(256) void bf16_prep_kernel(
    const float* __restrict__ depth0, const float* __restrict__ depth1,
    unsigned short* __restrict__ bf0, unsigned short* __restrict__ bf1)
{
    const int which = blockIdx.y;            // 0: depth0, 1: depth1
    const float* src = which ? depth1 : depth0;
    unsigned short* dst = which ? bf1 : bf0;
    const int n0 = (blockIdx.x * 256 + threadIdx.x) * 8;   // over BB*NPIX
    const float4* sp = (const float4*)(src + n0);
    float4 a = sp[0], b = sp[1];
    uint4 o;
    o.x = (unsigned int)f2bf_rne(a.x) | ((unsigned int)f2bf_rne(a.y) << 16);
    o.y = (unsigned int)f2bf_rne(a.z) | ((unsigned int)f2bf_rne(a.w) << 16);
    o.z = (unsigned int)f2bf_rne(b.x) | ((unsigned int)f2bf_rne(b.y) << 16);
    o.w = (unsigned int)f2bf_rne(b.z) | ((unsigned int)f2bf_rne(b.w) << 16);
    *(uint4*)(dst + n0) = o;
}

__global__ __launch_bounds__(BLK) void proj_depth_loss_kernel(
    const float* __restrict__ depth0, const float* __restrict__ depth1,
    const float* __restrict__ R0, const float* __restrict__ t0,
    const float* __restrict__ R1, const float* __restrict__ t1,
    const float* __restrict__ Km, const float* __restrict__ ray,
    const unsigned short* __restrict__ bf0, const unsigned short* __restrict__ bf1,
    float* __restrict__ partials)
{
    const int pass = blockIdx.z;
    const int b = blockIdx.y;
    const int n0 = (blockIdx.x * BLK + threadIdx.x) * PPT;

    const float* Ds = (pass == 0) ? depth0 : depth1;
    const unsigned short* Dt = (pass == 0) ? bf1 : bf0;   // gather from bf16 copy
    const float* Ra = (pass == 0) ? R0 : R1;
    const float* ta = (pass == 0) ? t0 : t1;
    const float* Rb = (pass == 0) ? R1 : R0;
    const float* tb = (pass == 0) ? t1 : t0;

    // Per-block uniform fold: uvd = d * (M r) + c,
    // M = K * Rb * Ra^T,  c = K * (tb - Rb * Ra^T * ta).
    const float* A = Ra + b * 9;
    const float* Bm = Rb + b * 9;
    float N_[9];  // N = Rb * Ra^T
    #pragma unroll
    for (int i = 0; i < 3; ++i)
        #pragma unroll
        for (int jj = 0; jj < 3; ++jj)
            N_[i*3+jj] = Bm[i*3+0]*A[jj*3+0] + Bm[i*3+1]*A[jj*3+1] + Bm[i*3+2]*A[jj*3+2];
    float tax=ta[b*3+0], tay=ta[b*3+1], taz=ta[b*3+2];
    float qx = tb[b*3+0] - (N_[0]*tax + N_[1]*tay + N_[2]*taz);
    float qy = tb[b*3+1] - (N_[3]*tax + N_[4]*tay + N_[5]*taz);
    float qz = tb[b*3+2] - (N_[6]*tax + N_[7]*tay + N_[8]*taz);
    float M_[9];
    #pragma unroll
    for (int i = 0; i < 3; ++i)
        #pragma unroll
        for (int jj = 0; jj < 3; ++jj)
            M_[i*3+jj] = Km[i*3+0]*N_[0*3+jj] + Km[i*3+1]*N_[1*3+jj] + Km[i*3+2]*N_[2*3+jj];
    float cx = Km[0]*qx + Km[1]*qy + Km[2]*qz;
    float cy = Km[3]*qx + Km[4]*qy + Km[5]*qz;
    float cz = Km[6]*qx + Km[7]*qy + Km[8]*qz;

    const float cwf = (float)WW / (float)(WW - 1);
    const float chf = (float)HH / (float)(HH - 1);

    // vector loads: depth (4 floats), ray (12 floats)
    float4 d4 = *(const float4*)(Ds + b * NPIX + n0);
    const float4* rp = (const float4*)(ray + 3 * n0);
    float4 r0 = rp[0], r1 = rp[1], r2 = rp[2];

    float dd[PPT] = {d4.x, d4.y, d4.z, d4.w};
    float rx[PPT] = {r0.x, r0.w, r1.z, r2.y};
    float ry[PPT] = {r0.y, r1.x, r1.w, r2.z};
    float rz[PPT] = {r0.z, r1.y, r2.x, r2.w};

    float ud[PPT], wxs[PPT], wyf[PPT];
    int base[PPT], dy1[PPT];

    #pragma unroll
    for (int i = 0; i < PPT; ++i) {
        float mrx = M_[0]*rx[i] + M_[1]*ry[i] + M_[2]*rz[i];
        float mry = M_[3]*rx[i] + M_[4]*ry[i] + M_[5]*rz[i];
        float mrz = M_[6]*rx[i] + M_[7]*ry[i] + M_[8]*rz[i];
        float ux = dd[i]*mrx + cx;
        float uy = dd[i]*mry + cy;
        float uu = dd[i]*mrz + cz;
        ud[i] = uu;

        float inv = __builtin_amdgcn_rcpf(fmaxf(uu, 0.0f) + 1e-12f);
        float sx = ux * inv * cwf - 0.5f;
        float sy = uy * inv * chf - 0.5f;
        sx = fminf(fmaxf(sx, 0.0f), (float)(WW - 1));
        sy = fminf(fmaxf(sy, 0.0f), (float)(HH - 1));
        float fx0 = floorf(sx);
        float fy0 = floorf(sy);
        float wxf = sx - fx0;
        wyf[i] = sy - fy0;
        int x0 = (int)fx0;
        int y0 = (int)fy0;
        // Pair-load: one 4B read gets {img[p], img[p+1]} as 2 bf16.
        // x0==W-1 implies wxf==0; shift window left 1, force weight 1.0.
        int atEdge = (x0 == WW - 1);
        base[i] = y0 * WW + x0 - atEdge;
        wxs[i] = atEdge ? 1.0f : wxf;
        dy1[i] = (y0 < HH - 1) ? WW : 0;
    }

    const unsigned short* img = Dt + b * NPIX;
    unsigned int tp[PPT], bp[PPT];
    #pragma unroll
    for (int i = 0; i < PPT; ++i) {
        tp[i] = ((const u32u*)(img + base[i]))->v;            // {v00, v01} bf16
        bp[i] = ((const u32u*)(img + base[i] + dy1[i]))->v;   // {v10, v11} bf16
    }

    float diff = 0.0f;
    #pragma unroll
    for (int i = 0; i < PPT; ++i) {
        float v00 = __uint_as_float(tp[i] << 16);
        float v01 = __uint_as_float(tp[i] & 0xffff0000u);
        float v10 = __uint_as_float(bp[i] << 16);
        float v11 = __uint_as_float(bp[i] & 0xffff0000u);
        float tv = v00 + wxs[i] * (v01 - v00);
        float bv = v10 + wxs[i] * (v11 - v10);
        float s = tv + wyf[i] * (bv - tv);
        diff += fabsf(ud[i] - s);
    }

    for (int off = 32; off > 0; off >>= 1)
        diff += __shfl_down(diff, off, 64);

    __shared__ float partial[BLK / 64];
    const int wave = threadIdx.x >> 6;
    const int lane = threadIdx.x & 63;
    if (lane == 0) partial[wave] = diff;
    __syncthreads();
    if (threadIdx.x == 0) {
        float s = partial[0] + partial[1] + partial[2] + partial[3];
        partials[blockIdx.x + GX * (blockIdx.y + BB * blockIdx.z)] = s;
    }
}

__global__ __launch_bounds__(1024) void reduce_partials_kernel(
    const float* __restrict__ partials, float* __restrict__ out)
{
    float s = 0.0f;
    for (int i = threadIdx.x; i < NPART; i += 1024) s += partials[i];
    for (int off = 32; off > 0; off >>= 1)
        s += __shfl_down(s, off, 64);
    __shared__ float partial[16];
    const int wave = threadIdx.x >> 6;
    const int lane = threadIdx.x & 63;
    if (lane == 0) partial[wave] = s;
    __syncthreads();
    if (threadIdx.x == 0) {
        float tot = 0.0f;
        #pragma unroll
        for (int i = 0; i < 16; ++i) tot += partial[i];
        out[0] = tot * (1.0f / (float)((long long)BB * NPIX));
    }
}

extern "C" void kernel_launch(void* const* d_in, const int* in_sizes, int n_in,
                              void* d_out, int out_size, void* d_ws, size_t ws_size,
                              hipStream_t stream) {
    const float* depth0 = (const float*)d_in[0];
    const float* depth1 = (const float*)d_in[1];
    const float* R0     = (const float*)d_in[2];
    const float* t0     = (const float*)d_in[3];
    const float* R1     = (const float*)d_in[4];
    const float* t1     = (const float*)d_in[5];
    const float* Km     = (const float*)d_in[6];
    const float* ray    = (const float*)d_in[7];
    float* out = (float*)d_out;
    char* ws = (char*)d_ws;

    unsigned short* bf0 = (unsigned short*)(ws + BF0_OFF);
    unsigned short* bf1 = (unsigned short*)(ws + BF1_OFF);
    float* partials     = (float*)(ws + PART_OFF);

    // prep: fp32 -> bf16 copies of both depth stacks
    dim3 pgrid((BB * NPIX) / (256 * 8), 2);
    bf16_prep_kernel<<<pgrid, dim3(256), 0, stream>>>(depth0, depth1, bf0, bf1);

    dim3 grid(GX, BB, 2);
    proj_depth_loss_kernel<<<grid, dim3(BLK), 0, stream>>>(
        depth0, depth1, R0, t0, R1, t1, Km, ray, bf0, bf1, partials);
    reduce_partials_kernel<<<1, 1024, 0, stream>>>(partials, out);
}